// Round 4
// baseline (456.689 us; speedup 1.0000x reference)
//
#include <hip/hip_runtime.h>
#include <hip/hip_bf16.h>
#include <math.h>

// Problem constants (fixed by the reference)
#define N_TOK 4096
#define DIM   1024
#define NEXP  16
#define HID   1536
#define TOPK2 2
#define NASSIGN (N_TOK * TOPK2)   // 8192

#define MAX_ITEMS 80      // worst-case sum_e ceil(ne/128) = 79
#define G1_BLOCKS (MAX_ITEMS * 12)          // 960 gemm1 tile blocks
#define G2_BLOCKS (MAX_ITEMS * 8)           // 640 gemm2 tile blocks

typedef __attribute__((ext_vector_type(8))) short short8;   // bf16x8 MFMA A/B frag
typedef __attribute__((ext_vector_type(4))) float floatx4;  // fp32x4 MFMA C/D frag
typedef unsigned short u16;

// async global->LDS, 16B per lane; LDS dest = wave-uniform base + lane*16
#define GLOAD_LDS16(gp, lp)                                                     \
    __builtin_amdgcn_global_load_lds(                                           \
        (const __attribute__((address_space(1))) unsigned int*)(gp),            \
        (__attribute__((address_space(3))) unsigned int*)(lp), 16, 0, 0)

__device__ __forceinline__ u16 bf16u(float f) {
    __hip_bfloat16 h = __float2bfloat16(f);
    return *(u16*)&h;
}

// 8 fp32 (two float4) -> 8 bf16 packed in a short8
__device__ __forceinline__ short8 cvt8(float4 a, float4 b) {
    short8 r;
    r[0] = (short)bf16u(a.x); r[1] = (short)bf16u(a.y);
    r[2] = (short)bf16u(a.z); r[3] = (short)bf16u(a.w);
    r[4] = (short)bf16u(b.x); r[5] = (short)bf16u(b.y);
    r[6] = (short)bf16u(b.z); r[7] = (short)bf16u(b.w);
    return r;
}

// ---------- Router: logits + top-2 + gates + x->bf16 ----------
// 256 blocks x 16 tokens. Thread (t,e) = (tid>>4, tid&15) accumulates one logit.
__global__ __launch_bounds__(256)
void router_kernel(const float* __restrict__ x, const float* __restrict__ rw,
                   int* __restrict__ idx, float* __restrict__ gate,
                   u16* __restrict__ x_bf) {
    int tid = threadIdx.x;
    int tb = blockIdx.x * 16;
    __shared__ float xs[16][68];
    __shared__ float rs[16][68];
    __shared__ float lg[16][17];

    int t = tid >> 4, e = tid & 15;
    int srow = tid >> 4, scol = (tid & 15) * 4;   // staging: one float4/thread

    float acc = 0.f;
    for (int k0 = 0; k0 < DIM; k0 += 64) {
        float4 xv = *(const float4*)&x[(size_t)(tb + srow) * DIM + k0 + scol];
        *(float4*)&xs[srow][scol] = xv;
        *(float4*)&rs[srow][scol] = *(const float4*)&rw[(size_t)srow * DIM + k0 + scol];
        {   // fused x -> bf16 (x is being read anyway)
            ushort4 o;
            o.x = bf16u(xv.x); o.y = bf16u(xv.y); o.z = bf16u(xv.z); o.w = bf16u(xv.w);
            *(ushort4*)&x_bf[(size_t)(tb + srow) * DIM + k0 + scol] = o;
        }
        __syncthreads();
        const float2* xp = (const float2*)xs[t];
        const float2* rp = (const float2*)rs[e];
        #pragma unroll
        for (int k = 0; k < 32; k++) {
            float2 a = xp[k], b = rp[k];
            acc = fmaf(a.x, b.x, acc);
            acc = fmaf(a.y, b.y, acc);
        }
        __syncthreads();
    }
    lg[t][e] = acc;
    __syncthreads();

    if (tid < 16) {
        int n = tb + tid;
        float v0 = -3.402823466e+38f, v1 = -3.402823466e+38f;
        int i0 = 0, i1 = 0;
        #pragma unroll
        for (int ee = 0; ee < NEXP; ee++) {
            float v = lg[tid][ee];
            if (v > v0) { v1 = v0; i1 = i0; v0 = v; i0 = ee; }
            else if (v > v1) { v1 = v; i1 = ee; }
        }
        float e1 = expf(v1 - v0);
        float inv = 1.f / (1.f + e1);
        idx[2 * n] = i0; idx[2 * n + 1] = i1;
        gate[2 * n] = inv; gate[2 * n + 1] = e1 * inv;
    }
}

// ---- Plan: counts/gsum -> offsets + aux + worklist + scatter + inverse map ----
__global__ __launch_bounds__(256)
void plan_kernel(const int* __restrict__ idx, const float* __restrict__ gate,
                 int* __restrict__ offsets, int* __restrict__ tlist,
                 int* __restrict__ slot_of,
                 int* __restrict__ wl, int* __restrict__ wcount,
                 float* __restrict__ aux_out) {
    __shared__ int cnt_s[16];
    __shared__ float gs_s[16];
    __shared__ int pos_s[16];
    __shared__ int offs_s[17];
    int tid = threadIdx.x;
    if (tid < 16) { cnt_s[tid] = 0; gs_s[tid] = 0.f; pos_s[tid] = 0; }
    __syncthreads();
    for (int i = tid; i < NASSIGN; i += 256) {
        int e = idx[i];
        atomicAdd(&cnt_s[e], 1);
        atomicAdd(&gs_s[e], gate[i]);
    }
    __syncthreads();
    if (tid == 0) {
        int acc = 0;
        for (int e = 0; e < NEXP; e++) { offs_s[e] = acc; acc += cnt_s[e]; }
        offs_s[NEXP] = acc;
        float tot = (float)acc;
        float s = 0.f;
        for (int e = 0; e < NEXP; e++) {
            float c = (float)cnt_s[e];
            s += (c / tot) * (gs_s[e] / fmaxf(c, 1.f));
        }
        *aux_out = 0.02f * (s / (float)NEXP);
        int m = 0;
        for (int e = 0; e < NEXP; e++) {
            int nt = (cnt_s[e] + 127) >> 7;
            for (int rt = 0; rt < nt; rt++) wl[m++] = (e << 8) | rt;
        }
        *wcount = m;
    }
    __syncthreads();
    if (tid < 17) offsets[tid] = offs_s[tid];
    for (int i = tid; i < NASSIGN; i += 256) {
        int e = idx[i];
        int p = atomicAdd(&pos_s[e], 1);
        int s = offs_s[e] + p;
        tlist[s] = i;
        slot_of[i] = s;
    }
}

__device__ __forceinline__ float gelu_tanh(float v) {
    float v3 = v * v * v;
    float t = tanhf(0.7978845608028654f * (v + 0.044715f * v3));
    return 0.5f * v * (1.f + t);
}

// =====================================================================
// MFMA grouped GEMM, 128x128 tile, BK=32, 4 waves (each 64x64).
// A (tokens/h): bf16 in HBM, staged via global_load_lds (linear dest,
//   pre-swizzled global koff).
// B (weights): fp32 in HBM, reg-staged: 4x float4 load -> cvt bf16 ->
//   2x ds_write_b128 into the SAME swizzled layout the reader uses.
//   Writer swizzle swz(row) = (row>>1)&3 on the 8-elem chunk index
//   (verified identical to the gload_lds koff invariant).
// Double-buffered; prefetch issued at step top, vmcnt waited after the
// MFMA cluster (issue-early / wait-late), one __syncthreads per step.
// This removes the standalone fp32->bf16 weight conversion passes
// (~300 MB HBM traffic + CU contention) entirely.
// =====================================================================

// GEMM1: h[a, :] = gelu(x[tok(a)] @ w1[e]^T + b1[e]),  K=DIM=1024, N=HID=1536
__global__ __launch_bounds__(256)
void gemm1_kernel(const u16* __restrict__ xb, const float* __restrict__ w1,
                  const float* __restrict__ b1,
                  const int* __restrict__ offsets, const int* __restrict__ tlist,
                  const int* __restrict__ wl, const int* __restrict__ wcount,
                  u16* __restrict__ h_bf) {
    int bid = blockIdx.x;
    int item = bid / 12;
    if (item >= *wcount) return;
    int colt = bid - item * 12;
    int w = wl[item];
    int e = w >> 8, rt = w & 255;
    int beg = offsets[e], ne = offsets[e + 1] - beg;
    int row0 = rt * 128, col0 = colt * 128;

    __shared__ u16 As[2][128 * 32];
    __shared__ u16 Bs[2][128 * 32];

    int tid = threadIdx.x;
    int wave = tid >> 6, lane = tid & 63;
    int wm = wave & 1, wn = wave >> 1;

    // ---- A: gather via global_load_lds, pre-swizzled koff ----
    int koff = (((lane & 3) ^ ((lane >> 3) & 3)) * 8);
    const u16* aptr[2];
    #pragma unroll
    for (int q = 0; q < 2; q++) {
        int lrow = wave * 32 + q * 16 + (lane >> 2);
        int gi = beg + row0 + lrow;
        int gi2 = (row0 + lrow < ne) ? gi : beg;     // clamp OOB rows to a valid row
        int tok = tlist[gi2] >> 1;
        aptr[q] = xb + (size_t)tok * DIM + koff;
    }

    // ---- B: fp32 reg-staging assignment ----
    int brow = tid >> 1;                 // 0..127: B row (= output col within tile)
    int bh   = tid & 1;                  // which 16-float half of the 32-float K-tile
    const float* bsrc = w1 + (size_t)(e * HID + col0 + brow) * DIM + bh * 16;
    int sz = (brow >> 1) & 3;
    int bc0 = (2 * bh) ^ sz;             // swizzled 8-elem chunk indices
    int bc1 = (2 * bh + 1) ^ sz;

    int rchunk = (((lane >> 4) ^ ((lane >> 1) & 3)) * 8);

    floatx4 acc[4][4] = {};
    float4 f0, f1, f2, f3;

    auto STAGE_A = [&](int kt, int b) {
        #pragma unroll
        for (int q = 0; q < 2; q++)
            GLOAD_LDS16(aptr[q] + kt * 32, &As[b][(wave * 32 + q * 16) * 32]);
    };
    auto LOAD_B = [&](int kt) {
        const float4* p = (const float4*)(bsrc + kt * 32);
        f0 = p[0]; f1 = p[1]; f2 = p[2]; f3 = p[3];
    };
    auto WRITE_B = [&](int b) {
        *(short8*)&Bs[b][brow * 32 + bc0 * 8] = cvt8(f0, f1);
        *(short8*)&Bs[b][brow * 32 + bc1 * 8] = cvt8(f2, f3);
    };
    auto CONSUME = [&](int b) {
        short8 af[4], bf_[4];
        #pragma unroll
        for (int mi = 0; mi < 4; mi++)
            af[mi] = *(const short8*)&As[b][(wm * 64 + mi * 16 + (lane & 15)) * 32 + rchunk];
        #pragma unroll
        for (int nj = 0; nj < 4; nj++)
            bf_[nj] = *(const short8*)&Bs[b][(wn * 64 + nj * 16 + (lane & 15)) * 32 + rchunk];
        #pragma unroll
        for (int mi = 0; mi < 4; mi++)
            #pragma unroll
            for (int nj = 0; nj < 4; nj++)
                acc[mi][nj] = __builtin_amdgcn_mfma_f32_16x16x32_bf16(af[mi], bf_[nj], acc[mi][nj], 0, 0, 0);
    };

    const int NT = DIM / 32;   // 32
    // prologue: tile 0
    LOAD_B(0); STAGE_A(0, 0); WRITE_B(0);
    __syncthreads();
    int cur = 0;
    for (int t = 0; t < NT - 1; ++t) {
        LOAD_B(t + 1);              // issue early (fp32 weight loads)
        STAGE_A(t + 1, cur ^ 1);    // issue early (async to LDS)
        CONSUME(cur);               // MFMA cluster covers the latency
        WRITE_B(cur ^ 1);           // compiler waits the B loads here
        __syncthreads();            // drains gload_lds + makes ds_writes visible
        cur ^= 1;
    }
    CONSUME(cur);

    #pragma unroll
    for (int mi = 0; mi < 4; mi++) {
        #pragma unroll
        for (int r = 0; r < 4; r++) {
            int lrow = wm * 64 + mi * 16 + (lane >> 4) * 4 + r;
            if (row0 + lrow >= ne) continue;
            size_t orow = (size_t)(beg + row0 + lrow);
            #pragma unroll
            for (int nj = 0; nj < 4; nj++) {
                int col = col0 + wn * 64 + nj * 16 + (lane & 15);
                float v = acc[mi][nj][r] + b1[e * HID + col];
                h_bf[orow * HID + col] = bf16u(gelu_tanh(v));
            }
        }
    }
}

// GEMM2: y[a] = gate(a) * (h[a] @ w2[e]^T + b2[e]),  K=HID=1536, N=DIM=1024
__global__ __launch_bounds__(256)
void gemm2_kernel(const u16* __restrict__ h_bf, const float* __restrict__ w2,
                  const float* __restrict__ b2,
                  const int* __restrict__ offsets, const int* __restrict__ tlist,
                  const int* __restrict__ wl, const int* __restrict__ wcount,
                  const float* __restrict__ gate, float* __restrict__ y) {
    int bid = blockIdx.x;
    int item = bid >> 3;
    if (item >= *wcount) return;
    int colt = bid & 7;
    int w = wl[item];
    int e = w >> 8, rt = w & 255;
    int beg = offsets[e], ne = offsets[e + 1] - beg;
    int row0 = rt * 128, col0 = colt * 128;

    __shared__ u16 As[2][128 * 32];
    __shared__ u16 Bs[2][128 * 32];

    int tid = threadIdx.x;
    int wave = tid >> 6, lane = tid & 63;
    int wm = wave & 1, wn = wave >> 1;

    int koff = (((lane & 3) ^ ((lane >> 3) & 3)) * 8);
    const u16* aptr[2];
    #pragma unroll
    for (int q = 0; q < 2; q++) {
        int lrow = wave * 32 + q * 16 + (lane >> 2);
        int gi = beg + row0 + lrow;
        int gi2 = (row0 + lrow < ne) ? gi : beg;
        aptr[q] = h_bf + (size_t)gi2 * HID + koff;
    }

    int brow = tid >> 1;
    int bh   = tid & 1;
    const float* bsrc = w2 + (size_t)(e * DIM + col0 + brow) * HID + bh * 16;
    int sz = (brow >> 1) & 3;
    int bc0 = (2 * bh) ^ sz;
    int bc1 = (2 * bh + 1) ^ sz;

    int rchunk = (((lane >> 4) ^ ((lane >> 1) & 3)) * 8);

    floatx4 acc[4][4] = {};
    float4 f0, f1, f2, f3;

    auto STAGE_A = [&](int kt, int b) {
        #pragma unroll
        for (int q = 0; q < 2; q++)
            GLOAD_LDS16(aptr[q] + kt * 32, &As[b][(wave * 32 + q * 16) * 32]);
    };
    auto LOAD_B = [&](int kt) {
        const float4* p = (const float4*)(bsrc + kt * 32);
        f0 = p[0]; f1 = p[1]; f2 = p[2]; f3 = p[3];
    };
    auto WRITE_B = [&](int b) {
        *(short8*)&Bs[b][brow * 32 + bc0 * 8] = cvt8(f0, f1);
        *(short8*)&Bs[b][brow * 32 + bc1 * 8] = cvt8(f2, f3);
    };
    auto CONSUME = [&](int b) {
        short8 af[4], bf_[4];
        #pragma unroll
        for (int mi = 0; mi < 4; mi++)
            af[mi] = *(const short8*)&As[b][(wm * 64 + mi * 16 + (lane & 15)) * 32 + rchunk];
        #pragma unroll
        for (int nj = 0; nj < 4; nj++)
            bf_[nj] = *(const short8*)&Bs[b][(wn * 64 + nj * 16 + (lane & 15)) * 32 + rchunk];
        #pragma unroll
        for (int mi = 0; mi < 4; mi++)
            #pragma unroll
            for (int nj = 0; nj < 4; nj++)
                acc[mi][nj] = __builtin_amdgcn_mfma_f32_16x16x32_bf16(af[mi], bf_[nj], acc[mi][nj], 0, 0, 0);
    };

    const int NT = HID / 32;   // 48
    LOAD_B(0); STAGE_A(0, 0); WRITE_B(0);
    __syncthreads();
    int cur = 0;
    for (int t = 0; t < NT - 1; ++t) {
        LOAD_B(t + 1);
        STAGE_A(t + 1, cur ^ 1);
        CONSUME(cur);
        WRITE_B(cur ^ 1);
        __syncthreads();
        cur ^= 1;
    }
    CONSUME(cur);

    #pragma unroll
    for (int mi = 0; mi < 4; mi++) {
        #pragma unroll
        for (int r = 0; r < 4; r++) {
            int lrow = wm * 64 + mi * 16 + (lane >> 4) * 4 + r;
            if (row0 + lrow >= ne) continue;
            int slot = beg + row0 + lrow;
            int t = tlist[slot];
            float g = gate[t];
            #pragma unroll
            for (int nj = 0; nj < 4; nj++) {
                int col = col0 + wn * 64 + nj * 16 + (lane & 15);
                float v = g * (acc[mi][nj][r] + b2[e * DIM + col]);
                y[(size_t)slot * DIM + col] = v;
            }
        }
    }
}

// out[t] = y[slot_of[2t]] + y[slot_of[2t+1]]  — pure streaming, fully coalesced
__global__ __launch_bounds__(256)
void combine_kernel(const float* __restrict__ y, const int* __restrict__ slot_of,
                    float* __restrict__ out) {
    int t = blockIdx.x;
    int c4 = threadIdx.x;                      // 256 float4 = 1024 floats
    int s0 = slot_of[2 * t], s1 = slot_of[2 * t + 1];
    float4 a = ((const float4*)(y + (size_t)s0 * DIM))[c4];
    float4 b = ((const float4*)(y + (size_t)s1 * DIM))[c4];
    float4 o;
    o.x = a.x + b.x; o.y = a.y + b.y; o.z = a.z + b.z; o.w = a.w + b.w;
    ((float4*)(out + (size_t)t * DIM))[c4] = o;
}

extern "C" void kernel_launch(void* const* d_in, const int* in_sizes, int n_in,
                              void* d_out, int out_size, void* d_ws, size_t ws_size,
                              hipStream_t stream) {
    const float* x  = (const float*)d_in[0];
    const float* rw = (const float*)d_in[1];
    const float* w1 = (const float*)d_in[2];
    const float* b1 = (const float*)d_in[3];
    const float* w2 = (const float*)d_in[4];
    const float* b2 = (const float*)d_in[5];
    float* out = (float*)d_out;   // fp32 output [N*D main | 1 aux]

    // ---- workspace layout (bytes) ----
    char* ws = (char*)d_ws;
    int*   offsets = (int*)(ws + 192);        // 17
    int*   wcount  = (int*)(ws + 384);        // 1
    int*   wl      = (int*)(ws + 512);        // up to 128
    int*   idx     = (int*)(ws + 4096);                               // 32 KB
    float* gate    = (float*)(ws + 4096 + 4 * NASSIGN);               // 32 KB
    int*   tlist   = (int*)(ws + 4096 + 8 * NASSIGN);                 // 32 KB
    int*   slot_of = (int*)(ws + 4096 + 12 * NASSIGN);                // 32 KB
    u16*   x_bf    = (u16*)(ws + (256 << 10));                        // 8.4 MB
    u16*   h_bf    = x_bf + (size_t)N_TOK * DIM;                      // +25.2 MB
    float* y       = (float*)(h_bf + (size_t)NASSIGN * HID);          // +33.5 MB
    // total need ~67.4 MB — well under the provided workspace

    router_kernel<<<N_TOK / 16, 256, 0, stream>>>(x, rw, idx, gate, x_bf);
    plan_kernel<<<1, 256, 0, stream>>>(idx, gate, offsets, tlist, slot_of,
                                       wl, wcount, out + (size_t)N_TOK * DIM);
    gemm1_kernel<<<G1_BLOCKS, 256, 0, stream>>>(
        x_bf, w1, b1, offsets, tlist, wl, wcount, h_bf);
    gemm2_kernel<<<G2_BLOCKS, 256, 0, stream>>>(
        h_bf, w2, b2, offsets, tlist, wl, wcount, gate, y);
    combine_kernel<<<N_TOK, 256, 0, stream>>>(y, slot_of, out);
}

// Round 5
// 419.253 us; speedup vs baseline: 1.0893x; 1.0893x over previous
//
#include <hip/hip_runtime.h>
#include <hip/hip_bf16.h>
#include <math.h>

// Problem constants (fixed by the reference)
#define N_TOK 4096
#define DIM   1024
#define NEXP  16
#define HID   1536
#define TOPK2 2
#define NASSIGN (N_TOK * TOPK2)   // 8192

// 64-row tiles: worst-case sum_e ceil(ne/64) = 128 + 15 partials <= 144
#define MAX_ITEMS 144
#define G1_BLOCKS (MAX_ITEMS * 12)          // 1728 gemm1 tile blocks (N=1536 -> 12 col tiles)
#define G2_BLOCKS (MAX_ITEMS * 8)           // 1152 gemm2 tile blocks (N=1024 -> 8 col tiles)
#define W_ELEMS   (NEXP * HID * DIM)        // 25,165,824 (w1 and w2 same size)
#define CVT_BLOCKS (W_ELEMS / 4 / 256)      // 24576 blocks of 256 float4-threads

typedef __attribute__((ext_vector_type(8))) short short8;   // bf16x8 MFMA A/B frag
typedef __attribute__((ext_vector_type(4))) float floatx4;  // fp32x4 MFMA C/D frag
typedef unsigned short u16;

// async global->LDS, 16B per lane; LDS dest = wave-uniform base + lane*16
#define GLOAD_LDS16(gp, lp)                                                     \
    __builtin_amdgcn_global_load_lds(                                           \
        (const __attribute__((address_space(1))) unsigned int*)(gp),            \
        (__attribute__((address_space(3))) unsigned int*)(lp), 16, 0, 0)

__device__ __forceinline__ u16 bf16u(float f) {
    __hip_bfloat16 h = __float2bfloat16(f);
    return *(u16*)&h;
}

__device__ __forceinline__ void cvt_one4(const float* __restrict__ src,
                                         u16* __restrict__ dst, int i) {
    float4 v = ((const float4*)src)[i];
    ushort4 o;
    o.x = bf16u(v.x); o.y = bf16u(v.y); o.z = bf16u(v.z); o.w = bf16u(v.w);
    ((ushort4*)dst)[i] = o;
}

// ---------- Router (blocks 0..255) + w1/w2 fp32->bf16 (remaining blocks) ----------
// Router is latency-bound on 256 blocks; the BW-bound weight conversion fills the
// rest of the machine and finishes well before gemm1/gemm2 need the bf16 weights.
__global__ __launch_bounds__(256)
void router_cvtw_kernel(const float* __restrict__ x, const float* __restrict__ rw,
                        int* __restrict__ idx, float* __restrict__ gate,
                        u16* __restrict__ x_bf,
                        const float* __restrict__ w1src, u16* __restrict__ w1dst,
                        const float* __restrict__ w2src, u16* __restrict__ w2dst) {
    int tid = threadIdx.x;
    if (blockIdx.x >= 256) {
        int c = blockIdx.x - 256;
        if (c < CVT_BLOCKS) cvt_one4(w1src, w1dst, c * 256 + tid);
        else                cvt_one4(w2src, w2dst, (c - CVT_BLOCKS) * 256 + tid);
        return;
    }
    int tb = blockIdx.x * 16;
    __shared__ float xs[16][68];
    __shared__ float rs[16][68];
    __shared__ float lg[16][17];

    int t = tid >> 4, e = tid & 15;
    int srow = tid >> 4, scol = (tid & 15) * 4;   // staging: one float4/thread

    float acc = 0.f;
    for (int k0 = 0; k0 < DIM; k0 += 64) {
        float4 xv = *(const float4*)&x[(size_t)(tb + srow) * DIM + k0 + scol];
        *(float4*)&xs[srow][scol] = xv;
        *(float4*)&rs[srow][scol] = *(const float4*)&rw[(size_t)srow * DIM + k0 + scol];
        {   // fused x -> bf16 (x is being read anyway)
            ushort4 o;
            o.x = bf16u(xv.x); o.y = bf16u(xv.y); o.z = bf16u(xv.z); o.w = bf16u(xv.w);
            *(ushort4*)&x_bf[(size_t)(tb + srow) * DIM + k0 + scol] = o;
        }
        __syncthreads();
        const float2* xp = (const float2*)xs[t];
        const float2* rp = (const float2*)rs[e];
        #pragma unroll
        for (int k = 0; k < 32; k++) {
            float2 a = xp[k], b = rp[k];
            acc = fmaf(a.x, b.x, acc);
            acc = fmaf(a.y, b.y, acc);
        }
        __syncthreads();
    }
    lg[t][e] = acc;
    __syncthreads();

    if (tid < 16) {
        int n = tb + tid;
        float v0 = -3.402823466e+38f, v1 = -3.402823466e+38f;
        int i0 = 0, i1 = 0;
        #pragma unroll
        for (int ee = 0; ee < NEXP; ee++) {
            float v = lg[tid][ee];
            if (v > v0) { v1 = v0; i1 = i0; v0 = v; i0 = ee; }
            else if (v > v1) { v1 = v; i1 = ee; }
        }
        float e1 = expf(v1 - v0);
        float inv = 1.f / (1.f + e1);
        idx[2 * n] = i0; idx[2 * n + 1] = i1;
        gate[2 * n] = inv; gate[2 * n + 1] = e1 * inv;
    }
}

// ---- Plan: counts/gsum -> offsets + aux + 64-row worklist + scatter + inverse ----
__global__ __launch_bounds__(256)
void plan_kernel(const int* __restrict__ idx, const float* __restrict__ gate,
                 int* __restrict__ offsets, int* __restrict__ tlist,
                 int* __restrict__ slot_of,
                 int* __restrict__ wl, int* __restrict__ wcount,
                 float* __restrict__ aux_out) {
    __shared__ int cnt_s[16];
    __shared__ float gs_s[16];
    __shared__ int pos_s[16];
    __shared__ int offs_s[17];
    int tid = threadIdx.x;
    if (tid < 16) { cnt_s[tid] = 0; gs_s[tid] = 0.f; pos_s[tid] = 0; }
    __syncthreads();
    for (int i = tid; i < NASSIGN; i += 256) {
        int e = idx[i];
        atomicAdd(&cnt_s[e], 1);
        atomicAdd(&gs_s[e], gate[i]);
    }
    __syncthreads();
    if (tid == 0) {
        int acc = 0;
        for (int e = 0; e < NEXP; e++) { offs_s[e] = acc; acc += cnt_s[e]; }
        offs_s[NEXP] = acc;
        float tot = (float)acc;
        float s = 0.f;
        for (int e = 0; e < NEXP; e++) {
            float c = (float)cnt_s[e];
            s += (c / tot) * (gs_s[e] / fmaxf(c, 1.f));
        }
        *aux_out = 0.02f * (s / (float)NEXP);
        int m = 0;
        for (int e = 0; e < NEXP; e++) {
            int nt = (cnt_s[e] + 63) >> 6;             // 64-row tiles
            for (int rt = 0; rt < nt; rt++) wl[m++] = (e << 8) | rt;
        }
        *wcount = m;
    }
    __syncthreads();
    if (tid < 17) offsets[tid] = offs_s[tid];
    for (int i = tid; i < NASSIGN; i += 256) {
        int e = idx[i];
        int p = atomicAdd(&pos_s[e], 1);
        int s = offs_s[e] + p;
        tlist[s] = i;
        slot_of[i] = s;
    }
}

__device__ __forceinline__ float gelu_tanh(float v) {
    float v3 = v * v * v;
    float t = tanhf(0.7978845608028654f * (v + 0.044715f * v3));
    return 0.5f * v * (1.f + t);
}

// =====================================================================
// MFMA grouped GEMM, 64x128 tile, BK=32 bf16, 4 waves (each 32x64 out).
// 64-row tiles double the grid (gemm1 ~1536, gemm2 ~1024 working blocks)
// -> 4+ blocks/CU (the VGPR-cap), doubling latency-hiding TLP, which the
// counters say is the binding constraint (Occ 21-28%, MfmaUtil 8-11%).
// LDS 24 KB: As 2x[64x32], Bs 2x[128x32]. Proven single-sync dbuf loop:
// stage tile t+1 into buf^1, consume buf, one __syncthreads per step.
// =====================================================================

// GEMM1: h[a, :] = gelu(x[tok(a)] @ w1[e]^T + b1[e]),  K=DIM=1024, N=HID=1536
__global__ __launch_bounds__(256)
void gemm1_kernel(const u16* __restrict__ xb, const u16* __restrict__ w1b,
                  const float* __restrict__ b1,
                  const int* __restrict__ offsets, const int* __restrict__ tlist,
                  const int* __restrict__ wl, const int* __restrict__ wcount,
                  u16* __restrict__ h_bf) {
    int bid = blockIdx.x;
    int item = bid / 12;
    if (item >= *wcount) return;
    int colt = bid - item * 12;
    int w = wl[item];
    int e = w >> 8, rt = w & 255;
    int beg = offsets[e], ne = offsets[e + 1] - beg;
    int row0 = rt * 64, col0 = colt * 128;

    __shared__ u16 As[2][64 * 32];
    __shared__ u16 Bs[2][128 * 32];

    int tid = threadIdx.x;
    int wave = tid >> 6, lane = tid & 63;
    int wm = wave & 1, wn = wave >> 1;

    int koff = (((lane & 3) ^ ((lane >> 3) & 3)) * 8);
    // A: one gload_lds per thread (64 rows x 64B)
    int lrowA = wave * 16 + (lane >> 2);
    int giA = (row0 + lrowA < ne) ? (beg + row0 + lrowA) : beg;   // clamp OOB rows
    const u16* aptr = xb + (size_t)(tlist[giA] >> 1) * DIM + koff;
    // B: two gload_lds per thread (128 rows x 64B)
    const u16* bptr[2];
    #pragma unroll
    for (int q = 0; q < 2; q++) {
        int lrowB = wave * 32 + q * 16 + (lane >> 2);
        int n = col0 + lrowB;                         // output col, always < HID
        bptr[q] = w1b + (size_t)(e * HID + n) * DIM + koff;
    }

    int rchunk = (((lane >> 4) ^ ((lane >> 1) & 3)) * 8);

    floatx4 acc[2][4] = {};

    auto STAGE = [&](int kt, int b) {
        GLOAD_LDS16(aptr + kt * 32, &As[b][(wave * 16) * 32]);
        #pragma unroll
        for (int q = 0; q < 2; q++)
            GLOAD_LDS16(bptr[q] + kt * 32, &Bs[b][(wave * 32 + q * 16) * 32]);
    };
    auto CONSUME = [&](int b) {
        short8 af[2], bf_[4];
        #pragma unroll
        for (int mi = 0; mi < 2; mi++)
            af[mi] = *(const short8*)&As[b][(wm * 32 + mi * 16 + (lane & 15)) * 32 + rchunk];
        #pragma unroll
        for (int nj = 0; nj < 4; nj++)
            bf_[nj] = *(const short8*)&Bs[b][(wn * 64 + nj * 16 + (lane & 15)) * 32 + rchunk];
        #pragma unroll
        for (int mi = 0; mi < 2; mi++)
            #pragma unroll
            for (int nj = 0; nj < 4; nj++)
                acc[mi][nj] = __builtin_amdgcn_mfma_f32_16x16x32_bf16(af[mi], bf_[nj], acc[mi][nj], 0, 0, 0);
    };

    const int NT = DIM / 32;   // 32
    STAGE(0, 0);
    __syncthreads();
    int cur = 0;
    for (int t = 0; t < NT; ++t) {
        if (t + 1 < NT) STAGE(t + 1, cur ^ 1);
        CONSUME(cur);
        __syncthreads();
        cur ^= 1;
    }

    #pragma unroll
    for (int mi = 0; mi < 2; mi++) {
        #pragma unroll
        for (int r = 0; r < 4; r++) {
            int lrow = wm * 32 + mi * 16 + (lane >> 4) * 4 + r;
            if (row0 + lrow >= ne) continue;
            size_t orow = (size_t)(beg + row0 + lrow);
            #pragma unroll
            for (int nj = 0; nj < 4; nj++) {
                int col = col0 + wn * 64 + nj * 16 + (lane & 15);
                float v = acc[mi][nj][r] + b1[e * HID + col];
                h_bf[orow * HID + col] = bf16u(gelu_tanh(v));
            }
        }
    }
}

// GEMM2: y[a] = gate(a) * (h[a] @ w2[e]^T + b2[e]),  K=HID=1536, N=DIM=1024
__global__ __launch_bounds__(256)
void gemm2_kernel(const u16* __restrict__ h_bf, const u16* __restrict__ w2b,
                  const float* __restrict__ b2,
                  const int* __restrict__ offsets, const int* __restrict__ tlist,
                  const int* __restrict__ wl, const int* __restrict__ wcount,
                  const float* __restrict__ gate, float* __restrict__ y) {
    int bid = blockIdx.x;
    int item = bid >> 3;
    if (item >= *wcount) return;
    int colt = bid & 7;
    int w = wl[item];
    int e = w >> 8, rt = w & 255;
    int beg = offsets[e], ne = offsets[e + 1] - beg;
    int row0 = rt * 64, col0 = colt * 128;

    __shared__ u16 As[2][64 * 32];
    __shared__ u16 Bs[2][128 * 32];

    int tid = threadIdx.x;
    int wave = tid >> 6, lane = tid & 63;
    int wm = wave & 1, wn = wave >> 1;

    int koff = (((lane & 3) ^ ((lane >> 3) & 3)) * 8);
    int lrowA = wave * 16 + (lane >> 2);
    int giA = (row0 + lrowA < ne) ? (beg + row0 + lrowA) : beg;
    const u16* aptr = h_bf + (size_t)giA * HID + koff;
    const u16* bptr[2];
    #pragma unroll
    for (int q = 0; q < 2; q++) {
        int lrowB = wave * 32 + q * 16 + (lane >> 2);
        int n = col0 + lrowB;                         // < DIM always
        bptr[q] = w2b + (size_t)(e * DIM + n) * HID + koff;
    }

    int rchunk = (((lane >> 4) ^ ((lane >> 1) & 3)) * 8);

    floatx4 acc[2][4] = {};

    auto STAGE = [&](int kt, int b) {
        GLOAD_LDS16(aptr + kt * 32, &As[b][(wave * 16) * 32]);
        #pragma unroll
        for (int q = 0; q < 2; q++)
            GLOAD_LDS16(bptr[q] + kt * 32, &Bs[b][(wave * 32 + q * 16) * 32]);
    };
    auto CONSUME = [&](int b) {
        short8 af[2], bf_[4];
        #pragma unroll
        for (int mi = 0; mi < 2; mi++)
            af[mi] = *(const short8*)&As[b][(wm * 32 + mi * 16 + (lane & 15)) * 32 + rchunk];
        #pragma unroll
        for (int nj = 0; nj < 4; nj++)
            bf_[nj] = *(const short8*)&Bs[b][(wn * 64 + nj * 16 + (lane & 15)) * 32 + rchunk];
        #pragma unroll
        for (int mi = 0; mi < 2; mi++)
            #pragma unroll
            for (int nj = 0; nj < 4; nj++)
                acc[mi][nj] = __builtin_amdgcn_mfma_f32_16x16x32_bf16(af[mi], bf_[nj], acc[mi][nj], 0, 0, 0);
    };

    const int NT = HID / 32;   // 48
    STAGE(0, 0);
    __syncthreads();
    int cur = 0;
    for (int t = 0; t < NT; ++t) {
        if (t + 1 < NT) STAGE(t + 1, cur ^ 1);
        CONSUME(cur);
        __syncthreads();
        cur ^= 1;
    }

    #pragma unroll
    for (int mi = 0; mi < 2; mi++) {
        #pragma unroll
        for (int r = 0; r < 4; r++) {
            int lrow = wm * 32 + mi * 16 + (lane >> 4) * 4 + r;
            if (row0 + lrow >= ne) continue;
            int slot = beg + row0 + lrow;
            int t = tlist[slot];
            float g = gate[t];
            #pragma unroll
            for (int nj = 0; nj < 4; nj++) {
                int col = col0 + wn * 64 + nj * 16 + (lane & 15);
                float v = g * (acc[mi][nj][r] + b2[e * DIM + col]);
                y[(size_t)slot * DIM + col] = v;
            }
        }
    }
}

// out[t] = y[slot_of[2t]] + y[slot_of[2t+1]]  — pure streaming, fully coalesced
__global__ __launch_bounds__(256)
void combine_kernel(const float* __restrict__ y, const int* __restrict__ slot_of,
                    float* __restrict__ out) {
    int t = blockIdx.x;
    int c4 = threadIdx.x;                      // 256 float4 = 1024 floats
    int s0 = slot_of[2 * t], s1 = slot_of[2 * t + 1];
    float4 a = ((const float4*)(y + (size_t)s0 * DIM))[c4];
    float4 b = ((const float4*)(y + (size_t)s1 * DIM))[c4];
    float4 o;
    o.x = a.x + b.x; o.y = a.y + b.y; o.z = a.z + b.z; o.w = a.w + b.w;
    ((float4*)(out + (size_t)t * DIM))[c4] = o;
}

extern "C" void kernel_launch(void* const* d_in, const int* in_sizes, int n_in,
                              void* d_out, int out_size, void* d_ws, size_t ws_size,
                              hipStream_t stream) {
    const float* x  = (const float*)d_in[0];
    const float* rw = (const float*)d_in[1];
    const float* w1 = (const float*)d_in[2];
    const float* b1 = (const float*)d_in[3];
    const float* w2 = (const float*)d_in[4];
    const float* b2 = (const float*)d_in[5];
    float* out = (float*)d_out;   // fp32 output [N*D main | 1 aux]

    // ---- workspace layout (bytes); same 134.5 MB footprint round 2 proved fits ----
    char* ws = (char*)d_ws;
    int*   offsets = (int*)(ws + 192);        // 17
    int*   wcount  = (int*)(ws + 384);        // 1
    int*   wl      = (int*)(ws + 512);        // up to 144 (3.5 KB available)
    int*   idx     = (int*)(ws + 4096);                               // 32 KB
    float* gate    = (float*)(ws + 4096 + 4 * NASSIGN);               // 32 KB
    int*   tlist   = (int*)(ws + 4096 + 8 * NASSIGN);                 // 32 KB
    int*   slot_of = (int*)(ws + 4096 + 12 * NASSIGN);                // 32 KB
    u16*   x_bf    = (u16*)(ws + (256 << 10));                        // 8.4 MB
    u16*   h_bf    = x_bf + (size_t)N_TOK * DIM;                      // +25.2 MB
    u16*   w1_bf   = h_bf + (size_t)NASSIGN * HID;                    // +50.3 MB
    u16*   w2_bf   = w1_bf + (size_t)W_ELEMS;                         // +50.3 MB
    // y (8192*1024 fp32 = 33.5 MB) aliases w1_bf (dead after gemm1)
    float* y       = (float*)w1_bf;

    // router + x->bf16, fused with BOTH weight conversions (front-loaded BW work
    // overlaps the latency-bound router; both gemms then run pure bf16).
    router_cvtw_kernel<<<256 + 2 * CVT_BLOCKS, 256, 0, stream>>>(
        x, rw, idx, gate, x_bf, w1, w1_bf, w2, w2_bf);
    plan_kernel<<<1, 256, 0, stream>>>(idx, gate, offsets, tlist, slot_of,
                                       wl, wcount, out + (size_t)N_TOK * DIM);
    gemm1_kernel<<<G1_BLOCKS, 256, 0, stream>>>(
        x_bf, w1_bf, b1, offsets, tlist, wl, wcount, h_bf);
    gemm2_kernel<<<G2_BLOCKS, 256, 0, stream>>>(
        h_bf, w2_bf, b2, offsets, tlist, wl, wcount, gate, y);
    combine_kernel<<<N_TOK, 256, 0, stream>>>(y, slot_of, out);
}